// Round 1
// baseline (790.645 us; speedup 1.0000x reference)
//
#include <hip/hip_runtime.h>

#define NODES 100000
#define INDIM 256
#define HDIM 128
#define ODIM 40

// ---------------- CSR build ----------------

__global__ void k_hist(const int* __restrict__ dst, int E, int* __restrict__ counts){
    int e = blockIdx.x * 256 + threadIdx.x;
    if(e < E) atomicAdd(&counts[dst[e]], 1);
}

// 256 blocks: per-chunk partial sums
__global__ void k_psum(const int* __restrict__ counts, int* __restrict__ partial, int n){
    __shared__ int sm[256];
    int chunk = (n + 255) >> 8;
    int start = blockIdx.x * chunk;
    int end = min(start + chunk, n);
    int s = 0;
    for(int i = start + threadIdx.x; i < end; i += 256) s += counts[i];
    sm[threadIdx.x] = s;
    __syncthreads();
    for(int off = 128; off > 0; off >>= 1){
        if(threadIdx.x < off) sm[threadIdx.x] += sm[threadIdx.x + off];
        __syncthreads();
    }
    if(threadIdx.x == 0) partial[blockIdx.x] = sm[0];
}

// single block: exclusive scan of the 256 partials
__global__ void k_scan256(const int* __restrict__ partial, int* __restrict__ pscan){
    __shared__ int sm[256];
    int t = threadIdx.x;
    sm[t] = partial[t];
    __syncthreads();
    for(int off = 1; off < 256; off <<= 1){
        int v = (t >= off) ? sm[t - off] : 0;
        __syncthreads();
        sm[t] += v;
        __syncthreads();
    }
    pscan[t] = (t == 0) ? 0 : sm[t - 1];
}

// 256 blocks x 512 threads: finalize row_start / cursor / dinv
__global__ void k_scan_final(const int* __restrict__ counts, const int* __restrict__ pscan,
                             int n, int E, int* __restrict__ row_start, int* __restrict__ cursor,
                             float* __restrict__ dinv){
    __shared__ int sm[512];
    int chunk = (n + 255) >> 8;
    int b = blockIdx.x, t = threadIdx.x;
    int idx = b * chunk + t;
    int c = (t < chunk && idx < n) ? counts[idx] : 0;
    sm[t] = c;
    __syncthreads();
    for(int off = 1; off < 512; off <<= 1){
        int v = (t >= off) ? sm[t - off] : 0;
        __syncthreads();
        sm[t] += v;
        __syncthreads();
    }
    if(t < chunk && idx < n){
        int rs = pscan[b] + sm[t] - c;   // exclusive
        row_start[idx] = rs;
        cursor[idx] = rs;
        dinv[idx] = rsqrtf((float)(c + 1));   // +1 self loop; deg >= 1 so max(,1e-12) moot
    }
    if(b == 0 && t == 0) row_start[n] = E;
}

__global__ void k_fill(const int* __restrict__ src, const int* __restrict__ dst, int E,
                       int* __restrict__ cursor, int* __restrict__ esrc){
    int e = blockIdx.x * 256 + threadIdx.x;
    if(e < E){
        int p = atomicAdd(&cursor[dst[e]], 1);
        esrc[p] = src[e];
    }
}

// ---------------- GEMM1: [N,256] @ [256,128] ----------------
// BM=128, BN=128, BK=16; 256 threads; 8x8 acc/thread via float2 LDS reads.
__global__ __launch_bounds__(256) void k_gemm1(const float* __restrict__ x, const float* __restrict__ W,
                                               float* __restrict__ h, int n){
    __shared__ float xs[16][132];   // [k][row], padded: stride 528B (16B aligned)
    __shared__ float ws[16][132];   // [k][col]
    int tid = threadIdx.x;
    int tx = tid & 15, ty = tid >> 4;
    int row0 = blockIdx.x * 128;
    float acc[8][8];
    #pragma unroll
    for(int i = 0; i < 8; ++i)
        #pragma unroll
        for(int j = 0; j < 8; ++j) acc[i][j] = 0.f;

    for(int k0 = 0; k0 < INDIM; k0 += 16){
        {   // x tile load (transpose into xs[k][r])
            int r = tid >> 2;
            int kq = (tid & 3) << 2;
            #pragma unroll
            for(int hh = 0; hh < 2; ++hh){
                int rr = r + 64 * hh;
                int grow = row0 + rr;
                float4 v = make_float4(0.f, 0.f, 0.f, 0.f);
                if(grow < n) v = *(const float4*)&x[(size_t)grow * INDIM + k0 + kq];
                xs[kq + 0][rr] = v.x;
                xs[kq + 1][rr] = v.y;
                xs[kq + 2][rr] = v.z;
                xs[kq + 3][rr] = v.w;
            }
        }
        {   // W tile load
            int k = tid >> 4;
            int c = (tid & 15) << 3;
            const float* wp = &W[(size_t)(k0 + k) * HDIM + c];
            *(float4*)&ws[k][c]     = *(const float4*)wp;
            *(float4*)&ws[k][c + 4] = *(const float4*)(wp + 4);
        }
        __syncthreads();
        #pragma unroll
        for(int k = 0; k < 16; ++k){
            float2 xv[4], wv[4];
            #pragma unroll
            for(int i = 0; i < 4; ++i) xv[i] = *(const float2*)&xs[k][32 * i + ty * 2];
            #pragma unroll
            for(int j = 0; j < 4; ++j) wv[j] = *(const float2*)&ws[k][32 * j + tx * 2];
            #pragma unroll
            for(int i = 0; i < 4; ++i){
                #pragma unroll
                for(int j = 0; j < 4; ++j){
                    acc[2*i+0][2*j+0] += xv[i].x * wv[j].x;
                    acc[2*i+0][2*j+1] += xv[i].x * wv[j].y;
                    acc[2*i+1][2*j+0] += xv[i].y * wv[j].x;
                    acc[2*i+1][2*j+1] += xv[i].y * wv[j].y;
                }
            }
        }
        __syncthreads();
    }
    #pragma unroll
    for(int i = 0; i < 4; ++i){
        #pragma unroll
        for(int ri = 0; ri < 2; ++ri){
            int row = row0 + 32 * i + ty * 2 + ri;
            if(row < n){
                #pragma unroll
                for(int j = 0; j < 4; ++j){
                    float2 o;
                    o.x = acc[2*i+ri][2*j+0];
                    o.y = acc[2*i+ri][2*j+1];
                    *(float2*)&h[(size_t)row * HDIM + 32 * j + tx * 2] = o;
                }
            }
        }
    }
}

// ---------------- GEMM2: [N,128] @ [128,40] ----------------
// BM=64, full K in LDS; thread = (row r, quarter q), 10 cols each.
__global__ __launch_bounds__(256) void k_gemm2(const float* __restrict__ a, const float* __restrict__ W,
                                               float* __restrict__ h, int n){
    __shared__ float xs[64][132];   // [row][k], stride 528B (16B aligned)
    __shared__ float ws[HDIM][ODIM];
    int tid = threadIdx.x;
    int row0 = blockIdx.x * 64;
    #pragma unroll
    for(int jj = 0; jj < 8; ++jj){
        int f = tid + 256 * jj;       // float4 index, 2048 total
        int r = f >> 5;
        int c4 = (f & 31) << 2;
        float4 v = make_float4(0.f, 0.f, 0.f, 0.f);
        int grow = row0 + r;
        if(grow < n) v = *(const float4*)&a[(size_t)grow * HDIM + c4];
        *(float4*)&xs[r][c4] = v;
    }
    #pragma unroll
    for(int jj = 0; jj < 5; ++jj){
        int f = tid + 256 * jj;       // 1280 float4 exact
        int r = f / 10;
        int c4 = (f % 10) << 2;
        *(float4*)&ws[r][c4] = *(const float4*)&W[(size_t)r * ODIM + c4];
    }
    __syncthreads();
    int q = tid & 3, r = tid >> 2;
    float acc[10];
    #pragma unroll
    for(int j = 0; j < 10; ++j) acc[j] = 0.f;
    #pragma unroll 4
    for(int k = 0; k < HDIM; ++k){
        float xv = xs[r][k];
        #pragma unroll
        for(int j = 0; j < 5; ++j){
            float2 w = *(const float2*)&ws[k][2 * q + 8 * j];
            acc[2*j+0] += xv * w.x;
            acc[2*j+1] += xv * w.y;
        }
    }
    int grow = row0 + r;
    if(grow < n){
        #pragma unroll
        for(int j = 0; j < 5; ++j){
            float2 o; o.x = acc[2*j]; o.y = acc[2*j+1];
            *(float2*)&h[(size_t)grow * ODIM + 2 * q + 8 * j] = o;
        }
    }
}

// ---------------- Aggregation (gather over CSR) ----------------
// layer1: dim 128, one wave/node, float2 per lane, +bias +relu
__global__ __launch_bounds__(256) void k_agg1(const float* __restrict__ h, const int* __restrict__ row_start,
                                              const int* __restrict__ esrc, const float* __restrict__ dinv,
                                              const float* __restrict__ bias, float* __restrict__ out, int n){
    int wid = (blockIdx.x * 256 + threadIdx.x) >> 6;
    int lane = threadIdx.x & 63;
    if(wid >= n) return;
    float di = dinv[wid];
    int c = lane * 2;
    float2 v = *(const float2*)&h[(size_t)wid * HDIM + c];
    float a0 = v.x * di, a1 = v.y * di;          // self loop contributes di*h[i]
    int e = row_start[wid], e1 = row_start[wid + 1];
    for(; e < e1; ++e){
        int s = esrc[e];
        float w = dinv[s];
        float2 m = *(const float2*)&h[(size_t)s * HDIM + c];
        a0 += m.x * w;
        a1 += m.y * w;
    }
    float2 o;
    o.x = fmaxf(a0 * di + bias[c],     0.f);
    o.y = fmaxf(a1 * di + bias[c + 1], 0.f);
    *(float2*)&out[(size_t)wid * HDIM + c] = o;
}

// layer2: dim 40, one wave/node (lanes 0..39), +bias, no relu
__global__ __launch_bounds__(256) void k_agg2(const float* __restrict__ h, const int* __restrict__ row_start,
                                              const int* __restrict__ esrc, const float* __restrict__ dinv,
                                              const float* __restrict__ bias, float* __restrict__ out, int n){
    int wid = (blockIdx.x * 256 + threadIdx.x) >> 6;
    int lane = threadIdx.x & 63;
    if(wid >= n || lane >= ODIM) return;
    float di = dinv[wid];
    float a = h[(size_t)wid * ODIM + lane] * di;
    int e = row_start[wid], e1 = row_start[wid + 1];
    for(; e < e1; ++e){
        int s = esrc[e];
        a += h[(size_t)s * ODIM + lane] * dinv[s];
    }
    out[(size_t)wid * ODIM + lane] = a * di + bias[lane];
}

extern "C" void kernel_launch(void* const* d_in, const int* in_sizes, int n_in,
                              void* d_out, int out_size, void* d_ws, size_t ws_size,
                              hipStream_t stream){
    const float* x  = (const float*)d_in[0];
    const int*   ei = (const int*)d_in[1];   // [2][E] int32 (JAX x64-disabled downcasts int64)
    const float* W1 = (const float*)d_in[2];
    const float* b1 = (const float*)d_in[3];
    const float* W2 = (const float*)d_in[4];
    const float* b2 = (const float*)d_in[5];
    float* out = (float*)d_out;

    const int n = NODES;
    const int E = in_sizes[1] / 2;
    const int* esrc_in = ei;
    const int* edst_in = ei + E;

    char* w = (char*)d_ws;
    int*   counts    = (int*)(w + (0u << 19));           // 400 KB
    int*   row_start = (int*)(w + (1u << 19));           // 400 KB (+1)
    int*   cursor    = (int*)(w + (2u << 19));           // 400 KB
    int*   partial   = (int*)(w + (3u << 19));           // 1 KB
    int*   pscan     = (int*)(w + (3u << 19) + 4096);    // 1 KB
    float* dinv      = (float*)(w + (4u << 19));         // 400 KB
    int*   esrc      = (int*)(w + (5u << 19));           // 6.4 MB
    float* h1        = (float*)(w + (16u << 20));        // 51.2 MB  [N,128]
    float* h1r       = (float*)(w + (68u << 20));        // 51.2 MB  [N,128]
    float* h2        = h1;                                // reuse (h1 dead after agg1), 16 MB

    hipMemsetAsync(counts, 0, n * sizeof(int), stream);
    k_hist<<<(E + 255) / 256, 256, 0, stream>>>(edst_in, E, counts);
    k_psum<<<256, 256, 0, stream>>>(counts, partial, n);
    k_scan256<<<1, 256, 0, stream>>>(partial, pscan);
    k_scan_final<<<256, 512, 0, stream>>>(counts, pscan, n, E, row_start, cursor, dinv);
    k_fill<<<(E + 255) / 256, 256, 0, stream>>>(esrc_in, edst_in, E, cursor, esrc);

    k_gemm1<<<(n + 127) / 128, 256, 0, stream>>>(x, W1, h1, n);
    k_agg1<<<(n * 64 + 255) / 256, 256, 0, stream>>>(h1, row_start, esrc, dinv, b1, h1r, n);
    k_gemm2<<<(n + 63) / 64, 256, 0, stream>>>(h1r, W2, h2, n);
    k_agg2<<<(n * 64 + 255) / 256, 256, 0, stream>>>(h2, row_start, esrc, dinv, b2, out, n);
}

// Round 3
// 655.101 us; speedup vs baseline: 1.2069x; 1.2069x over previous
//
#include <hip/hip_runtime.h>

#define NODES 100000
#define INDIM 256
#define HDIM 128
#define ODIM 40

// ---------------- CSR build ----------------

__global__ void k_hist(const int* __restrict__ dst, int E, int* __restrict__ counts){
    int e = blockIdx.x * 256 + threadIdx.x;
    if(e < E) atomicAdd(&counts[dst[e]], 1);
}

// 256 blocks: per-chunk partial sums
__global__ void k_psum(const int* __restrict__ counts, int* __restrict__ partial, int n){
    __shared__ int sm[256];
    int chunk = (n + 255) >> 8;
    int start = blockIdx.x * chunk;
    int end = min(start + chunk, n);
    int s = 0;
    for(int i = start + threadIdx.x; i < end; i += 256) s += counts[i];
    sm[threadIdx.x] = s;
    __syncthreads();
    for(int off = 128; off > 0; off >>= 1){
        if(threadIdx.x < off) sm[threadIdx.x] += sm[threadIdx.x + off];
        __syncthreads();
    }
    if(threadIdx.x == 0) partial[blockIdx.x] = sm[0];
}

// single block: exclusive scan of the 256 partials
__global__ void k_scan256(const int* __restrict__ partial, int* __restrict__ pscan){
    __shared__ int sm[256];
    int t = threadIdx.x;
    sm[t] = partial[t];
    __syncthreads();
    for(int off = 1; off < 256; off <<= 1){
        int v = (t >= off) ? sm[t - off] : 0;
        __syncthreads();
        sm[t] += v;
        __syncthreads();
    }
    pscan[t] = (t == 0) ? 0 : sm[t - 1];
}

// 256 blocks x 512 threads: finalize row_start / cursor / dinv
__global__ void k_scan_final(const int* __restrict__ counts, const int* __restrict__ pscan,
                             int n, int E, int* __restrict__ row_start, int* __restrict__ cursor,
                             float* __restrict__ dinv){
    __shared__ int sm[512];
    int chunk = (n + 255) >> 8;
    int b = blockIdx.x, t = threadIdx.x;
    int idx = b * chunk + t;
    int c = (t < chunk && idx < n) ? counts[idx] : 0;
    sm[t] = c;
    __syncthreads();
    for(int off = 1; off < 512; off <<= 1){
        int v = (t >= off) ? sm[t - off] : 0;
        __syncthreads();
        sm[t] += v;
        __syncthreads();
    }
    if(t < chunk && idx < n){
        int rs = pscan[b] + sm[t] - c;   // exclusive
        row_start[idx] = rs;
        cursor[idx] = rs;
        dinv[idx] = rsqrtf((float)(c + 1));   // +1 self loop
    }
    if(b == 0 && t == 0) row_start[n] = E;
}

__global__ void k_fill(const int* __restrict__ src, const int* __restrict__ dst, int E,
                       int* __restrict__ cursor, int* __restrict__ esrc){
    int e = blockIdx.x * 256 + threadIdx.x;
    if(e < E){
        int p = atomicAdd(&cursor[dst[e]], 1);
        esrc[p] = src[e];
    }
}

// ---------------- GEMM1: h' = dinv .* (x @ W1), [N,256]@[256,128] ----------------
__global__ __launch_bounds__(256) void k_gemm1(const float* __restrict__ x, const float* __restrict__ W,
                                               const float* __restrict__ dinv,
                                               float* __restrict__ h, int n){
    __shared__ float xs[16][132];   // [k][row]
    __shared__ float ws[16][132];   // [k][col]
    int tid = threadIdx.x;
    int tx = tid & 15, ty = tid >> 4;
    int row0 = blockIdx.x * 128;
    float acc[8][8];
    #pragma unroll
    for(int i = 0; i < 8; ++i)
        #pragma unroll
        for(int j = 0; j < 8; ++j) acc[i][j] = 0.f;

    for(int k0 = 0; k0 < INDIM; k0 += 16){
        {   // x tile load (transpose into xs[k][r])
            int r = tid >> 2;
            int kq = (tid & 3) << 2;
            #pragma unroll
            for(int hh = 0; hh < 2; ++hh){
                int rr = r + 64 * hh;
                int grow = row0 + rr;
                float4 v = make_float4(0.f, 0.f, 0.f, 0.f);
                if(grow < n) v = *(const float4*)&x[(size_t)grow * INDIM + k0 + kq];
                xs[kq + 0][rr] = v.x;
                xs[kq + 1][rr] = v.y;
                xs[kq + 2][rr] = v.z;
                xs[kq + 3][rr] = v.w;
            }
        }
        {   // W tile load
            int k = tid >> 4;
            int c = (tid & 15) << 3;
            const float* wp = &W[(size_t)(k0 + k) * HDIM + c];
            *(float4*)&ws[k][c]     = *(const float4*)wp;
            *(float4*)&ws[k][c + 4] = *(const float4*)(wp + 4);
        }
        __syncthreads();
        #pragma unroll
        for(int k = 0; k < 16; ++k){
            float4 xv[2], wv[2];
            #pragma unroll
            for(int i = 0; i < 2; ++i) xv[i] = *(const float4*)&xs[k][64 * i + ty * 4];
            #pragma unroll
            for(int j = 0; j < 2; ++j) wv[j] = *(const float4*)&ws[k][64 * j + tx * 4];
            #pragma unroll
            for(int i = 0; i < 2; ++i){
                #pragma unroll
                for(int j = 0; j < 2; ++j){
                    const float* xp = (const float*)&xv[i];
                    const float* wp = (const float*)&wv[j];
                    #pragma unroll
                    for(int rr = 0; rr < 4; ++rr)
                        #pragma unroll
                        for(int cc = 0; cc < 4; ++cc)
                            acc[4*i+rr][4*j+cc] += xp[rr] * wp[cc];
                }
            }
        }
        __syncthreads();
    }
    #pragma unroll
    for(int i = 0; i < 2; ++i){
        #pragma unroll
        for(int rr = 0; rr < 4; ++rr){
            int row = row0 + 64 * i + ty * 4 + rr;
            if(row < n){
                float dv = dinv[row];
                #pragma unroll
                for(int j = 0; j < 2; ++j){
                    float4 o;
                    o.x = acc[4*i+rr][4*j+0] * dv;
                    o.y = acc[4*i+rr][4*j+1] * dv;
                    o.z = acc[4*i+rr][4*j+2] * dv;
                    o.w = acc[4*i+rr][4*j+3] * dv;
                    *(float4*)&h[(size_t)row * HDIM + 64 * j + tx * 4] = o;
                }
            }
        }
    }
}

// ---------------- GEMM2: h' = dinv .* (a @ W2), [N,128]@[128,40] ----------------
__global__ __launch_bounds__(256) void k_gemm2(const float* __restrict__ a, const float* __restrict__ W,
                                               const float* __restrict__ dinv,
                                               float* __restrict__ h, int n){
    __shared__ float xs[64][132];
    __shared__ float ws[HDIM][ODIM];
    int tid = threadIdx.x;
    int row0 = blockIdx.x * 64;
    #pragma unroll
    for(int jj = 0; jj < 8; ++jj){
        int f = tid + 256 * jj;       // float4 index, 2048 total
        int r = f >> 5;
        int c4 = (f & 31) << 2;
        float4 v = make_float4(0.f, 0.f, 0.f, 0.f);
        int grow = row0 + r;
        if(grow < n) v = *(const float4*)&a[(size_t)grow * HDIM + c4];
        *(float4*)&xs[r][c4] = v;
    }
    #pragma unroll
    for(int jj = 0; jj < 5; ++jj){
        int f = tid + 256 * jj;       // 1280 float4 exact
        int r = f / 10;
        int c4 = (f % 10) << 2;
        *(float4*)&ws[r][c4] = *(const float4*)&W[(size_t)r * ODIM + c4];
    }
    __syncthreads();
    int q = tid & 3, r = tid >> 2;
    float acc[10];
    #pragma unroll
    for(int j = 0; j < 10; ++j) acc[j] = 0.f;
    #pragma unroll 4
    for(int k = 0; k < HDIM; ++k){
        float xv = xs[r][k];
        #pragma unroll
        for(int j = 0; j < 5; ++j){
            float2 w = *(const float2*)&ws[k][2 * q + 8 * j];
            acc[2*j+0] += xv * w.x;
            acc[2*j+1] += xv * w.y;
        }
    }
    int grow = row0 + r;
    if(grow < n){
        float dv = dinv[grow];
        #pragma unroll
        for(int j = 0; j < 5; ++j){
            float2 o; o.x = acc[2*j] * dv; o.y = acc[2*j+1] * dv;
            *(float2*)&h[(size_t)grow * ODIM + 2 * q + 8 * j] = o;
        }
    }
}

// ---------------- Aggregation (gather over CSR, rows pre-scaled by dinv[src]) ----------------
// layer1: dim 128, one wave/node, float2 per lane; out = relu(di*sum + b)
__global__ __launch_bounds__(256) void k_agg1(const float* __restrict__ h, const int* __restrict__ row_start,
                                              const int* __restrict__ esrc, const float* __restrict__ dinv,
                                              const float* __restrict__ bias, float* __restrict__ out, int n){
    int wid = (blockIdx.x * 256 + threadIdx.x) >> 6;
    int lane = threadIdx.x & 63;
    if(wid >= n) return;
    int c = lane * 2;
    float2 v = *(const float2*)&h[(size_t)wid * HDIM + c];
    float a0 = v.x, a1 = v.y;                      // self loop: h'[i]
    int e = row_start[wid], e1 = row_start[wid + 1];
    for(; e + 4 <= e1; e += 4){
        int s0 = esrc[e], s1 = esrc[e+1], s2 = esrc[e+2], s3 = esrc[e+3];
        float2 m0 = *(const float2*)&h[(size_t)s0 * HDIM + c];
        float2 m1 = *(const float2*)&h[(size_t)s1 * HDIM + c];
        float2 m2 = *(const float2*)&h[(size_t)s2 * HDIM + c];
        float2 m3 = *(const float2*)&h[(size_t)s3 * HDIM + c];
        a0 += (m0.x + m1.x) + (m2.x + m3.x);
        a1 += (m0.y + m1.y) + (m2.y + m3.y);
    }
    for(; e < e1; ++e){
        int s = esrc[e];
        float2 m = *(const float2*)&h[(size_t)s * HDIM + c];
        a0 += m.x; a1 += m.y;
    }
    float di = dinv[wid];
    float2 o;
    o.x = fmaxf(fmaf(a0, di, bias[c]),     0.f);
    o.y = fmaxf(fmaf(a1, di, bias[c + 1]), 0.f);
    *(float2*)&out[(size_t)wid * HDIM + c] = o;
}

// layer2: dim 40, one wave/node (lanes 0..39)
__global__ __launch_bounds__(256) void k_agg2(const float* __restrict__ h, const int* __restrict__ row_start,
                                              const int* __restrict__ esrc, const float* __restrict__ dinv,
                                              const float* __restrict__ bias, float* __restrict__ out, int n){
    int wid = (blockIdx.x * 256 + threadIdx.x) >> 6;
    int lane = threadIdx.x & 63;
    if(wid >= n || lane >= ODIM) return;
    float a = h[(size_t)wid * ODIM + lane];        // self loop: h'[i]
    int e = row_start[wid], e1 = row_start[wid + 1];
    for(; e + 4 <= e1; e += 4){
        int s0 = esrc[e], s1 = esrc[e+1], s2 = esrc[e+2], s3 = esrc[e+3];
        float m0 = h[(size_t)s0 * ODIM + lane];
        float m1 = h[(size_t)s1 * ODIM + lane];
        float m2 = h[(size_t)s2 * ODIM + lane];
        float m3 = h[(size_t)s3 * ODIM + lane];
        a += (m0 + m1) + (m2 + m3);
    }
    for(; e < e1; ++e){
        int s = esrc[e];
        a += h[(size_t)s * ODIM + lane];
    }
    out[(size_t)wid * ODIM + lane] = fmaf(a, dinv[wid], bias[lane]);
}

extern "C" void kernel_launch(void* const* d_in, const int* in_sizes, int n_in,
                              void* d_out, int out_size, void* d_ws, size_t ws_size,
                              hipStream_t stream){
    const float* x  = (const float*)d_in[0];
    const int*   ei = (const int*)d_in[1];   // [2][E] int32
    const float* W1 = (const float*)d_in[2];
    const float* b1 = (const float*)d_in[3];
    const float* W2 = (const float*)d_in[4];
    const float* b2 = (const float*)d_in[5];
    float* out = (float*)d_out;

    const int n = NODES;
    const int E = in_sizes[1] / 2;
    const int* esrc_in = ei;
    const int* edst_in = ei + E;

    char* w = (char*)d_ws;
    int*   counts    = (int*)(w + (0u << 19));           // 400 KB
    int*   row_start = (int*)(w + (1u << 19));           // 400 KB (+1)
    int*   cursor    = (int*)(w + (2u << 19));           // 400 KB
    int*   partial   = (int*)(w + (3u << 19));           // 1 KB
    int*   pscan     = (int*)(w + (3u << 19) + 4096);    // 1 KB
    float* dinv      = (float*)(w + (4u << 19));         // 400 KB
    int*   esrc      = (int*)(w + (5u << 19));           // 6.4 MB
    float* h1        = (float*)(w + (16u << 20));        // 51.2 MB  [N,128] (pre-scaled)
    float* h1r       = (float*)(w + (68u << 20));        // 51.2 MB  [N,128]
    float* h2        = h1;                                // reuse, 16 MB

    hipMemsetAsync(counts, 0, n * sizeof(int), stream);
    k_hist<<<(E + 255) / 256, 256, 0, stream>>>(edst_in, E, counts);
    k_psum<<<256, 256, 0, stream>>>(counts, partial, n);
    k_scan256<<<1, 256, 0, stream>>>(partial, pscan);
    k_scan_final<<<256, 512, 0, stream>>>(counts, pscan, n, E, row_start, cursor, dinv);
    k_fill<<<(E + 255) / 256, 256, 0, stream>>>(esrc_in, edst_in, E, cursor, esrc);

    k_gemm1<<<(n + 127) / 128, 256, 0, stream>>>(x, W1, dinv, h1, n);
    k_agg1<<<(n * 64 + 255) / 256, 256, 0, stream>>>(h1, row_start, esrc, dinv, b1, h1r, n);
    k_gemm2<<<(n + 63) / 64, 256, 0, stream>>>(h1r, W2, dinv, h2, n);
    k_agg2<<<(n * 64 + 255) / 256, 256, 0, stream>>>(h2, row_start, esrc, dinv, b2, out, n);
}